// Round 5
// baseline (315.512 us; speedup 1.0000x reference)
//
#include <hip/hip_runtime.h>

#define S 132                 // padded LDS row stride (floats) for gemm tiles
#define SCALE 10.0f           // 1 / TEMPERATURE
#define EPS_MARGIN 0.008f     // 2 * (bf16 unit-dot hard error bound)
#define SROWS_CAP 480         // per-strip flagged-row cap (expect ~170 now)
#define ROWCHUNK 48           // rows per rescreen chunk (3 x 16-row MFMA tiles)
#define STRIP_CAND 256        // per-strip candidate cap (expect ~85)

typedef __attribute__((ext_vector_type(8))) short short8;
typedef __attribute__((ext_vector_type(4))) float floatx4;
typedef __attribute__((ext_vector_type(16))) float floatx16;

#define MFMA16(a, b, c) __builtin_amdgcn_mfma_f32_16x16x32_bf16((a), (b), (c), 0, 0, 0)
#define MFMA32(a, b, c) __builtin_amdgcn_mfma_f32_32x32x16_bf16((a), (b), (c), 0, 0, 0)

// ---------- helpers ----------
__device__ __forceinline__ unsigned int ordered_bits(float f) {
    unsigned int b = __float_as_uint(f);
    return (b & 0x80000000u) ? ~b : (b | 0x80000000u);
}
__device__ __forceinline__ float from_ordered(unsigned int u) {
    return __uint_as_float((u & 0x80000000u) ? (u ^ 0x80000000u) : ~u);
}
__device__ __forceinline__ short bf_rne(float x) {   // fp32 -> bf16 bits, RNE
    unsigned int u = __float_as_uint(x);
    return (short)((u + 0x7FFFu + ((u >> 16) & 1u)) >> 16);
}
__device__ __forceinline__ float bf2f(short s) {
    return __uint_as_float(((unsigned int)(unsigned short)s) << 16);
}

// ---------- K1: l2-normalize p1,p2 -> pn fp32 + pnb bf16; init state --------
__global__ void k_prep(const float* __restrict__ p1, const float* __restrict__ p2,
                       float* __restrict__ pn, short* __restrict__ pnb,
                       unsigned int* __restrict__ mbest,
                       unsigned long long* __restrict__ best,
                       unsigned int* __restrict__ scnt,
                       float* __restrict__ sums) {
    int row = blockIdx.x;               // 0..4095
    int t = threadIdx.x;                // 0..63
    const float* src = (row < 2048) ? (p1 + (size_t)row * 128)
                                    : (p2 + (size_t)(row - 2048) * 128);
    float2 v = ((const float2*)src)[t];
    float ss = v.x * v.x + v.y * v.y;
    #pragma unroll
    for (int o = 32; o; o >>= 1) ss += __shfl_xor(ss, o);
    float inv = 1.0f / sqrtf(ss);
    float2 o2; o2.x = v.x * inv; o2.y = v.y * inv;
    ((float2*)(pn + (size_t)row * 128))[t] = o2;
    unsigned int pk = (unsigned int)(unsigned short)bf_rne(o2.x)
                    | ((unsigned int)(unsigned short)bf_rne(o2.y) << 16);
    ((unsigned int*)(pnb + (size_t)row * 128))[t] = pk;
    if (t == 0) { mbest[row] = 0u; best[row] = 0ULL; if (row < 1024) scnt[row] = 0u; }
    if (row < 128) sums[row * 64 + t] = 0.0f;
}

// ---------- K2: queue fp32 -> qb bf16 ----------
__global__ void k_qcvt(const float* __restrict__ queue, short* __restrict__ qb) {
    size_t i = ((size_t)blockIdx.x * 256 + threadIdx.x) * 8;
    float4 f0 = *(const float4*)(queue + i);
    float4 f1 = *(const float4*)(queue + i + 4);
    short8 o;
    o[0] = bf_rne(f0.x); o[1] = bf_rne(f0.y); o[2] = bf_rne(f0.z); o[3] = bf_rne(f0.w);
    o[4] = bf_rne(f1.x); o[5] = bf_rne(f1.y); o[6] = bf_rne(f1.z); o[7] = bf_rne(f1.w);
    *(short8*)(qb + i) = o;
}

// ---------- 32x32 screen compute step: one 32-q tile, 2 row-frags ------------
__device__ __forceinline__ void screen_tile32(const short8 A[2][8], const short8 B[8],
                                              floatx16& rm0, floatx16& rm1) {
    floatx16 zero = {0.0f, 0.0f, 0.0f, 0.0f, 0.0f, 0.0f, 0.0f, 0.0f,
                     0.0f, 0.0f, 0.0f, 0.0f, 0.0f, 0.0f, 0.0f, 0.0f};
    floatx16 acc0 = MFMA32(A[0][0], B[0], zero);
    floatx16 acc1 = MFMA32(A[1][0], B[0], zero);
    #pragma unroll
    for (int kk = 1; kk < 8; ++kk) {
        acc0 = MFMA32(A[0][kk], B[kk], acc0);
        acc1 = MFMA32(A[1][kk], B[kk], acc1);
    }
    #pragma unroll
    for (int r = 0; r < 16; ++r) {
        rm0[r] = fmaxf(rm0[r], acc0[r]);
        rm1[r] = fmaxf(rm1[r], acc1[r]);
    }
}

// ---------- K3: single bf16 MFMA screen pass (32x32x16) ----------------------
// Grid 1024 = 16 rowblocks (256 rows) x 64 qsplits; block = 4 waves, wave owns
// 64 rows (A[2][8] = 64 VGPR) x 1024-q strip. launch_bounds(256,2). Switched
// 16x16x32 -> 32x32x16: half the MFMA issue slots per q (16 MFMA / 32-q tile),
// +15% MFMA ceiling (2382 vs 2075 TF), denser acc (f32x16). B double-buffered
// in registers; all 4 waves read identical B addresses (L1 shared); qsub=g>>4
// so consecutive blocks share a strip. Epilogue: exact fp32 strip-max ->
// smax[strip][row] (pruning certificate), per-row mbest via atomicMax.
// NOTE: 32x32 accumulation order differs from k_rescreen's 16x16 -> screen and
// rescreen scores differ by <= e32+e16 <= EPS_MARGIN; k_rows' flag test is
// loosened by EPS_MARGIN to keep the certificate sound.
__global__ __launch_bounds__(256, 2) void k_screen(const short* __restrict__ pnb,
                                                   const short* __restrict__ qb,
                                                   unsigned int* __restrict__ mbest,
                                                   float* __restrict__ smax) {
    int tid = threadIdx.x;
    int lane = tid & 63, wv = tid >> 6;
    int l31 = lane & 31, hi = lane >> 5;

    int id = blockIdx.x;                // 0..1023
    int xcd = id & 7;
    int g = id >> 3;                    // 0..127
    int rowblk = g & 15;                // 16 rowblocks of 256 rows
    int qsub = g >> 4;                  // 0..7 (consecutive g share a strip)
    int qsplit = xcd * 8 + qsub;        // strip of 1024 q, XCD-local
    int rowbase = rowblk * 256 + wv * 64;
    int qstart = qsplit * 1024;

    // A fragments: 2 row-groups x 8 k-groups. mfma_32x32x16 A layout:
    // lane holds row = l31, k = kk*16 + hi*8 + j (j=0..7 contiguous bf16).
    short8 A[2][8];
    #pragma unroll
    for (int rf = 0; rf < 2; ++rf) {
        const short* ap = pnb + (size_t)(rowbase + rf * 32 + l31) * 128 + hi * 8;
        #pragma unroll
        for (int kk = 0; kk < 8; ++kk)
            A[rf][kk] = *(const short8*)(ap + kk * 16);
    }
    #pragma unroll
    for (int rf = 0; rf < 2; ++rf)
        #pragma unroll
        for (int kk = 0; kk < 8; ++kk)
            asm volatile("" : "+v"(A[rf][kk]));   // keep A resident (neutral insurance)

    floatx16 rm0, rm1;
    #pragma unroll
    for (int r = 0; r < 16; ++r) { rm0[r] = -1e30f; rm1[r] = -1e30f; }

    // B: same fragment convention (col = l31, k = kk*16 + hi*8 + j), B^T input.
    const short* lp = qb + (size_t)(qstart + l31) * 128 + hi * 8;
    short8 Ba[8], Bb[8];
    #pragma unroll
    for (int kk = 0; kk < 8; ++kk) Ba[kk] = *(const short8*)(lp + kk * 16);

    for (int t = 0; t < 32; t += 2) {   // 32 tiles of 32 q
        if ((t & 7) == 0) __syncthreads();     // keep waves converged for B sharing
        const short* p1p = lp + 4096;          // tile t+1
        #pragma unroll
        for (int kk = 0; kk < 8; ++kk) Bb[kk] = *(const short8*)(p1p + kk * 16);
        screen_tile32(A, Ba, rm0, rm1);        // compute tile t
        const short* p2p = lp + 8192;          // tile t+2 (tail over-read -> pnb region)
        #pragma unroll
        for (int kk = 0; kk < 8; ++kk) Ba[kk] = *(const short8*)(p2p + kk * 16);
        screen_tile32(A, Bb, rm0, rm1);        // compute tile t+1
        lp += 8192;
    }

    // Row-max reduce across the 32 q-columns (lanes sharing hi), then write.
    // C/D layout (m74/m101): col = l31, row = (r&3) + 8*(r>>2) + 4*hi.
    #pragma unroll
    for (int rf = 0; rf < 2; ++rf)
        #pragma unroll
        for (int r = 0; r < 16; ++r) {
            float v = rf ? rm1[r] : rm0[r];
            v = fmaxf(v, __shfl_xor(v, 1));
            v = fmaxf(v, __shfl_xor(v, 2));
            v = fmaxf(v, __shfl_xor(v, 4));
            v = fmaxf(v, __shfl_xor(v, 8));
            v = fmaxf(v, __shfl_xor(v, 16));
            if (l31 == 0) {
                int row = rowbase + rf * 32 + (r & 3) + 8 * (r >> 2) + 4 * hi;
                atomicMax(&mbest[row], ordered_bits(v));
                smax[(size_t)qsplit * 4096 + row] = v;   // exact fp32 strip max
            }
        }
}

// ---------- K4a: per-strip flagged-row list (built ONCE per strip) ----------
// Flag test loosened by EPS_MARGIN: smax holds 32x32-order scores while the
// rescreen re-scores with 16x16 order; |screen - rescreen| <= EPS_MARGIN.
__global__ __launch_bounds__(256) void k_rows(const unsigned int* __restrict__ mbest,
                                              const float* __restrict__ smax,
                                              int* __restrict__ rcnt,
                                              unsigned short* __restrict__ rlist) {
    __shared__ unsigned short rows[SROWS_CAP];
    __shared__ int nsh;
    int tid = threadIdx.x;
    int s = blockIdx.x;                 // strip 0..63
    if (tid == 0) nsh = 0;
    __syncthreads();
    const float* sm = smax + (size_t)s * 4096;
    #pragma unroll
    for (int j = 0; j < 16; ++j) {
        int row = tid + 256 * j;
        float thr = from_ordered(mbest[row]) - 2.0f * EPS_MARGIN;
        if (sm[row] > thr) {
            int pos = atomicAdd(&nsh, 1);
            if (pos < SROWS_CAP) rows[pos] = (unsigned short)row;
        }
    }
    __syncthreads();
    int n = nsh; if (n > SROWS_CAP) n = SROWS_CAP;
    if (tid == 0) rcnt[s] = n;
    for (int i = tid; i < n; i += 256) rlist[s * SROWS_CAP + i] = rows[i];
}

// ---------- K4b: flagged-row rescreen -> exact candidate list ----------------
// Grid 1024 = 64 strips x 16 qparts (all live). Each wave owns one q-tile
// (B frags loaded ONCE), loops over row chunks of 48. Per-strip counters +
// banks avoid a single hot atomic line. 16x16 scoring; pass threshold
// mbest - EPS covers the cross-order error (see k_screen note).
__global__ __launch_bounds__(256, 4) void k_rescreen(const short* __restrict__ pnb,
                                                     const short* __restrict__ qb,
                                                     const unsigned int* __restrict__ mbest,
                                                     const int* __restrict__ rcnt,
                                                     const unsigned short* __restrict__ rlist,
                                                     unsigned int* __restrict__ scnt,
                                                     unsigned int* __restrict__ cand) {
    int b = blockIdx.x;
    int s = b & 63;
    int qp = b >> 6;                    // 0..15
    int n = rcnt[s];
    if (n == 0) return;

    int tid = threadIdx.x;
    int lane = tid & 63, wv = tid >> 6;
    int n16 = lane & 15, quad = lane >> 4;
    int qt = qp * 4 + wv;               // q-tile 0..63 within strip
    int qrow = s * 1024 + qt * 16 + n16;    // this lane's q column index

    const short* bp = qb + (size_t)qrow * 128 + quad * 8;
    short8 b0 = *(const short8*)(bp);
    short8 b1 = *(const short8*)(bp + 32);
    short8 b2 = *(const short8*)(bp + 64);
    short8 b3 = *(const short8*)(bp + 96);

    const unsigned short* rl = rlist + s * SROWS_CAP;
    for (int base = 0; base < n; base += ROWCHUNK) {
        // Fixed 3 row-tiles (static indexing -> registers); invalid lanes get
        // a clamped A row and thr=+inf so they never push.
        short8 Af[3][4]; float th[3][4]; int rowC[3][4];
        #pragma unroll
        for (int rt = 0; rt < 3; ++rt) {
            int ia = base + rt * 16 + n16;
            int rA = rl[ia < n ? ia : base];
            const short* ap = pnb + (size_t)rA * 128 + quad * 8;
            #pragma unroll
            for (int kk = 0; kk < 4; ++kk) Af[rt][kk] = *(const short8*)(ap + kk * 32);
            #pragma unroll
            for (int r = 0; r < 4; ++r) {
                int ic = base + rt * 16 + quad * 4 + r;
                if (ic < n) {
                    int rr = rl[ic];
                    rowC[rt][r] = rr;
                    th[rt][r] = from_ordered(mbest[rr]) - EPS_MARGIN;
                } else { rowC[rt][r] = 0; th[rt][r] = 3.0e38f; }
            }
        }
        #pragma unroll
        for (int rt = 0; rt < 3; ++rt) {
            floatx4 zero = {0.0f, 0.0f, 0.0f, 0.0f};
            floatx4 acc = MFMA16(Af[rt][0], b0, zero);
            acc = MFMA16(Af[rt][1], b1, acc);
            acc = MFMA16(Af[rt][2], b2, acc);
            acc = MFMA16(Af[rt][3], b3, acc);
            #pragma unroll
            for (int r = 0; r < 4; ++r) {
                if (acc[r] > th[rt][r]) {
                    unsigned int pos = atomicAdd(&scnt[s * 16], 1u);
                    if (pos < STRIP_CAND)
                        cand[s * STRIP_CAND + pos] =
                            ((unsigned int)rowC[rt][r] << 16) | (unsigned int)(qrow & 0xFFFF);
                }
            }
        }
    }
}

// ---------- K5: exact fp32 re-rank of candidates ----------
// Grid 256 = 64 strips x 4 blocks; 16 waves per strip loop over its slots.
__global__ void k_rerank(const float* __restrict__ pn, const float* __restrict__ queue,
                         const unsigned int* __restrict__ scnt,
                         const unsigned int* __restrict__ cand,
                         unsigned long long* __restrict__ best) {
    int lane = threadIdx.x & 63, wv = threadIdx.x >> 6;
    int s = blockIdx.x >> 2;
    int wq = ((blockIdx.x & 3) << 2) | wv;          // 0..15 within strip
    unsigned int c = scnt[s * 16]; if (c > STRIP_CAND) c = STRIP_CAND;
    for (unsigned int slot = wq; slot < c; slot += 16) {
        unsigned int v = cand[s * STRIP_CAND + slot];
        unsigned int row = v >> 16;
        unsigned int q = v & 0xFFFFu;               // Q=65536 fits 16 bits
        float2 a = ((const float2*)(pn + (size_t)row * 128))[lane];
        float2 b = ((const float2*)(queue + (size_t)q * 128))[lane];
        float d = a.x * b.x + a.y * b.y;
        #pragma unroll
        for (int o = 32; o; o >>= 1) d += __shfl_xor(d, o);
        if (lane == 0) {
            unsigned long long pk = ((unsigned long long)ordered_bits(d) << 32)
                                  | (unsigned long long)(unsigned int)(~q);
            atomicMax(&best[row], pk);
        }
    }
}

// ---------- K6: gather nn rows from queue -> bf16 ----------
__global__ void k_gather(const float* __restrict__ queue,
                         const unsigned long long* __restrict__ best,
                         short* __restrict__ nnb) {
    int row = blockIdx.x;
    int t = threadIdx.x;
    unsigned int idx = ~(unsigned int)(best[row] & 0xFFFFFFFFull);
    idx &= 0xFFFFu;
    float2 v = ((const float2*)(queue + (size_t)idx * 128))[t];
    unsigned int pk = (unsigned int)(unsigned short)bf_rne(v.x)
                    | ((unsigned int)(unsigned short)bf_rne(v.y) << 16);
    ((unsigned int*)(nnb + (size_t)row * 128))[t] = pk;
}

// ---------- K7: fused A(bf16) @ B(fp32)^T -> exp-partial row/col sums --------
__global__ __launch_bounds__(256) void k_gemm_lse(const short* __restrict__ Ab,
                                                  const float* __restrict__ B,
                                                  float* __restrict__ rowsum,
                                                  float* __restrict__ colsum,
                                                  float* __restrict__ diag) {
    __shared__ __align__(16) float al[64 * S];
    __shared__ __align__(16) float bl[64 * S];
    __shared__ float red[64][17];
    int tid = threadIdx.x;
    const short8* asrc = (const short8*)(Ab + (size_t)blockIdx.x * 64 * 128);
    #pragma unroll
    for (int i = tid; i < 1024; i += 256) {
        short8 v = asrc[i];
        int r = i >> 4, c = (i & 15) * 8;
        float* dst = &al[r * S + c];
        #pragma unroll
        for (int j = 0; j < 8; ++j) dst[j] = bf2f(v[j]);
    }
    const float4* bsrc = (const float4*)(B + (size_t)blockIdx.y * 64 * 128);
    #pragma unroll
    for (int i = tid; i < 2048; i += 256) {
        int r = i >> 5, c = i & 31;
        *(float4*)&bl[r * S + c * 4] = bsrc[i];
    }
    __syncthreads();
    int ty = tid >> 4, tx = tid & 15;
    float acc[4][4] = {};
    #pragma unroll 2
    for (int k = 0; k < 128; k += 4) {
        float4 a[4], b[4];
        #pragma unroll
        for (int i = 0; i < 4; ++i) a[i] = *(const float4*)&al[(ty + 16 * i) * S + k];
        #pragma unroll
        for (int j = 0; j < 4; ++j) b[j] = *(const float4*)&bl[(tx + 16 * j) * S + k];
        #pragma unroll
        for (int i = 0; i < 4; ++i)
            #pragma unroll
            for (int j = 0; j < 4; ++j)
                acc[i][j] += a[i].x * b[j].x + a[i].y * b[j].y +
                             a[i].z * b[j].z + a[i].w * b[j].w;
    }
    int rowbase = blockIdx.x * 64, colbase = blockIdx.y * 64;

    float e[4][4], rs[4], cs[4];
    #pragma unroll
    for (int i = 0; i < 4; ++i) { rs[i] = 0.0f; cs[i] = 0.0f; }
    #pragma unroll
    for (int i = 0; i < 4; ++i)
        #pragma unroll
        for (int j = 0; j < 4; ++j) {
            e[i][j] = __expf(acc[i][j] * SCALE - 10.0f);
            rs[i] += e[i][j];
        }
    #pragma unroll
    for (int j = 0; j < 4; ++j)
        #pragma unroll
        for (int i = 0; i < 4; ++i) cs[j] += e[i][j];

    if (rowbase == colbase && ty == tx) {
        #pragma unroll
        for (int i = 0; i < 4; ++i) diag[rowbase + ty + 16 * i] = acc[i][i];
    }

    #pragma unroll
    for (int i = 0; i < 4; ++i) red[ty + 16 * i][tx] = rs[i];
    __syncthreads();
    if (tid < 64) {
        float s = 0.0f;
        #pragma unroll
        for (int x = 0; x < 16; ++x) s += red[tid][x];
        atomicAdd(&rowsum[rowbase + tid], s);
    }
    __syncthreads();
    #pragma unroll
    for (int j = 0; j < 4; ++j) red[tx + 16 * j][ty] = cs[j];
    __syncthreads();
    if (tid < 64) {
        float s = 0.0f;
        #pragma unroll
        for (int x = 0; x < 16; ++x) s += red[tid][x];
        atomicAdd(&colsum[colbase + tid], s);
    }
}

// ---------- K8: final loss ----------
__global__ void k_final(const float* __restrict__ sums,
                        const float* __restrict__ dg1, const float* __restrict__ dg2,
                        float* __restrict__ out) {
    int idx = blockIdx.x * 256 + threadIdx.x;    // 0..8191
    int seg = idx >> 11, r = idx & 2047;
    float s = sums[seg * 2048 + r];
    float d = (seg < 2) ? dg1[r] : dg2[r];
    out[idx] = 10.0f + logf(s) - d * SCALE;
}

extern "C" void kernel_launch(void* const* d_in, const int* in_sizes, int n_in,
                              void* d_out, int out_size, void* d_ws, size_t ws_size,
                              hipStream_t stream) {
    const float* p1    = (const float*)d_in[0];   // [2048,128]
    const float* p2    = (const float*)d_in[1];   // [2048,128]
    const float* queue = (const float*)d_in[2];   // [65536,128]
    float* out = (float*)d_out;                   // [8192]

    char* w = (char*)d_ws;                        // footprint ~20.25 MiB
    float* pn  = (float*)w;                               // 2 MB fp32 [4096,128]
    short* nnb = (short*)(w + (2u << 20));                // 1 MB bf16 [4096,128]
    short* qb  = (short*)(w + (3u << 20));                // 16 MB bf16 [65536,128]
    short* pnb = (short*)(w + (19u << 20));               // 1 MB bf16 [4096,128]
    char* b2 = w + (20u << 20);
    unsigned int* mbest = (unsigned int*)b2;                        // 16 KB
    unsigned long long* best = (unsigned long long*)(b2 + (16u << 10)); // 32 KB
    unsigned int* scnt = (unsigned int*)(b2 + (48u << 10));         // 4 KB (64 x 16 u32, 64B stride)
    int* rcnt = (int*)(b2 + (52u << 10));                           // 4 KB (64 used)
    unsigned short* rlist = (unsigned short*)(b2 + (56u << 10));    // 60 KB (64 x 480 u16)
    unsigned int* cand = (unsigned int*)(b2 + (116u << 10));        // 64 KB (64 x 256 u32)
    float* sums = (float*)(b2 + (180u << 10));                      // 32 KB
    float* dg1  = sums + 8192;                                      // 8 KB
    float* dg2  = dg1 + 2048;                                       // 8 KB
    // smax [64 strips][4096 rows] fp32 = 1 MB, overlaid on nnb (1 MB):
    // last smax read is k_rescreen; nnb first written by k_gather (later in
    // stream order) -> no conflict.
    float* smax = (float*)nnb;

    k_prep<<<4096, 64, 0, stream>>>(p1, p2, pn, pnb, mbest, best, scnt, sums);
    k_qcvt<<<4096, 256, 0, stream>>>(queue, qb);
    k_screen<<<1024, 256, 0, stream>>>(pnb, qb, mbest, smax);
    k_rows<<<64, 256, 0, stream>>>(mbest, smax, rcnt, rlist);
    k_rescreen<<<64 * 16, 256, 0, stream>>>(pnb, qb, mbest, rcnt, rlist, scnt, cand);
    k_rerank<<<256, 256, 0, stream>>>(pn, queue, scnt, cand, best);
    k_gather<<<4096, 64, 0, stream>>>(queue, best, nnb);

    // M1 = nn1 @ p2n^T : rows -> loss[0..2047], cols -> loss[2048..4095]
    k_gemm_lse<<<dim3(32, 32), 256, 0, stream>>>(nnb, pn + 2048 * 128,
                                                 sums, sums + 2048, dg1);
    // M2 = nn2 @ p1n^T : rows -> loss[4096..6143], cols -> loss[6144..8191]
    k_gemm_lse<<<dim3(32, 32), 256, 0, stream>>>(nnb + 2048 * 128, pn,
                                                 sums + 4096, sums + 6144, dg2);
    k_final<<<32, 256, 0, stream>>>(sums, dg1, dg2, out);
}

// Round 6
// 234.832 us; speedup vs baseline: 1.3436x; 1.3436x over previous
//
#include <hip/hip_runtime.h>

#define S 132                 // padded LDS row stride (floats) for gemm tiles
#define SCALE 10.0f           // 1 / TEMPERATURE
#define EPS_MARGIN 0.008f     // 2 * (bf16 unit-dot hard error bound)
#define SROWS_CAP 480         // per-strip flagged-row cap (expect ~85, sd ~9)
#define ROWCHUNK 48           // rows per rescreen chunk (3 x 16-row MFMA tiles)

typedef __attribute__((ext_vector_type(8))) short short8;
typedef __attribute__((ext_vector_type(4))) float floatx4;

#define MFMA16(a, b, c) __builtin_amdgcn_mfma_f32_16x16x32_bf16((a), (b), (c), 0, 0, 0)

// ---------- helpers ----------
__device__ __forceinline__ unsigned int ordered_bits(float f) {
    unsigned int b = __float_as_uint(f);
    return (b & 0x80000000u) ? ~b : (b | 0x80000000u);
}
__device__ __forceinline__ float from_ordered(unsigned int u) {
    return __uint_as_float((u & 0x80000000u) ? (u ^ 0x80000000u) : ~u);
}
__device__ __forceinline__ short bf_rne(float x) {   // fp32 -> bf16 bits, RNE
    unsigned int u = __float_as_uint(x);
    return (short)((u + 0x7FFFu + ((u >> 16) & 1u)) >> 16);
}
__device__ __forceinline__ float bf2f(short s) {
    return __uint_as_float(((unsigned int)(unsigned short)s) << 16);
}

// ---------- K1: fused prep (l2-norm + init) and queue bf16 convert ----------
// Blocks 0..1023: 4 rows each (wave per row) -> pn fp32 + pnb bf16, init
// mbest/best, zero sums. Blocks 1024..5119: qcvt (queue fp32 -> qb bf16).
__global__ __launch_bounds__(256) void k_prep_qcvt(const float* __restrict__ p1,
                                                   const float* __restrict__ p2,
                                                   const float* __restrict__ queue,
                                                   float* __restrict__ pn,
                                                   short* __restrict__ pnb,
                                                   short* __restrict__ qb,
                                                   unsigned int* __restrict__ mbest,
                                                   unsigned long long* __restrict__ best,
                                                   float* __restrict__ sums) {
    int b = blockIdx.x;
    if (b < 1024) {
        int sub = threadIdx.x >> 6;     // wave 0..3 -> one row each
        int t = threadIdx.x & 63;
        int row = b * 4 + sub;          // 0..4095
        const float* src = (row < 2048) ? (p1 + (size_t)row * 128)
                                        : (p2 + (size_t)(row - 2048) * 128);
        float2 v = ((const float2*)src)[t];
        float ss = v.x * v.x + v.y * v.y;
        #pragma unroll
        for (int o = 32; o; o >>= 1) ss += __shfl_xor(ss, o);
        float inv = 1.0f / sqrtf(ss);
        float2 o2; o2.x = v.x * inv; o2.y = v.y * inv;
        ((float2*)(pn + (size_t)row * 128))[t] = o2;
        unsigned int pk = (unsigned int)(unsigned short)bf_rne(o2.x)
                        | ((unsigned int)(unsigned short)bf_rne(o2.y) << 16);
        ((unsigned int*)(pnb + (size_t)row * 128))[t] = pk;
        if (t == 0) { mbest[row] = 0u; best[row] = 0ULL; }
        if (row < 128) sums[row * 64 + t] = 0.0f;
    } else {
        size_t i = ((size_t)(b - 1024) * 256 + threadIdx.x) * 8;
        float4 f0 = *(const float4*)(queue + i);
        float4 f1 = *(const float4*)(queue + i + 4);
        short8 o;
        o[0] = bf_rne(f0.x); o[1] = bf_rne(f0.y); o[2] = bf_rne(f0.z); o[3] = bf_rne(f0.w);
        o[4] = bf_rne(f1.x); o[5] = bf_rne(f1.y); o[6] = bf_rne(f1.z); o[7] = bf_rne(f1.w);
        *(short8*)(qb + i) = o;
    }
}

// ---------- screen compute step: 16-q tile, k-outer / rf-inner (8-way ILP) ---
__device__ __forceinline__ void screen_tile(const short8 A[8][4],
                                            short8 b0, short8 b1, short8 b2, short8 b3,
                                            float rmax[8][4]) {
    floatx4 acc[8];
    floatx4 zero = {0.0f, 0.0f, 0.0f, 0.0f};
    #pragma unroll
    for (int rf = 0; rf < 8; ++rf) acc[rf] = MFMA16(A[rf][0], b0, zero);
    #pragma unroll
    for (int rf = 0; rf < 8; ++rf) acc[rf] = MFMA16(A[rf][1], b1, acc[rf]);
    #pragma unroll
    for (int rf = 0; rf < 8; ++rf) acc[rf] = MFMA16(A[rf][2], b2, acc[rf]);
    #pragma unroll
    for (int rf = 0; rf < 8; ++rf) acc[rf] = MFMA16(A[rf][3], b3, acc[rf]);
    #pragma unroll
    for (int rf = 0; rf < 8; ++rf)
        #pragma unroll
        for (int r = 0; r < 4; ++r) rmax[rf][r] = fmaxf(rmax[rf][r], acc[rf][r]);
}

// ---------- K2: single bf16 MFMA screen pass (round-2 proven structure) ------
// 512 blocks = 8 rowblocks x 64 qsplits, 4 waves/block, wave owns 128 rows
// (A[8][4] = 128 VGPR), B double-buffered in registers, launch_bounds(256,2).
// Epilogue stores exact fp32 strip-max to smax[strip][row] (pruning
// certificate). Accumulation order identical to k_rescreen -> bit-exact.
__global__ __launch_bounds__(256, 2) void k_screen(const short* __restrict__ pnb,
                                                   const short* __restrict__ qb,
                                                   unsigned int* __restrict__ mbest,
                                                   float* __restrict__ smax) {
    int tid = threadIdx.x;
    int lane = tid & 63, wv = tid >> 6;
    int n16 = lane & 15, quad = lane >> 4;

    int id = blockIdx.x;                // 0..511
    int xcd = id & 7;
    int g = id >> 3;                    // 0..63
    int rowblk = g & 7;                 // 8 rowblocks of 512 rows
    int qsub = g >> 3;                  // 0..7
    int qsplit = xcd * 8 + qsub;        // 64 qsplits of 1024 q, XCD-local
    int rowbase = rowblk * 512 + wv * 128;
    int qstart = qsplit * 1024;

    // A fragments: 8 row-groups x 4 k-groups, direct bf16 short8 loads.
    short8 A[8][4];
    #pragma unroll
    for (int rf = 0; rf < 8; ++rf) {
        const short* ap = pnb + (size_t)(rowbase + rf * 16 + n16) * 128 + quad * 8;
        #pragma unroll
        for (int kk = 0; kk < 4; ++kk)
            A[rf][kk] = *(const short8*)(ap + kk * 32);
    }
    #pragma unroll
    for (int rf = 0; rf < 8; ++rf)
        #pragma unroll
        for (int kk = 0; kk < 4; ++kk)
            asm volatile("" : "+v"(A[rf][kk]));   // keep A resident (neutral insurance)

    float rmax[8][4];
    #pragma unroll
    for (int rf = 0; rf < 8; ++rf)
        #pragma unroll
        for (int r = 0; r < 4; ++r) rmax[rf][r] = -1e30f;

    const short* lp = qb + (size_t)(qstart + n16) * 128 + quad * 8;
    // B buffer set 0 <- tile 0
    short8 a0 = *(const short8*)(lp), a1 = *(const short8*)(lp + 32),
           a2 = *(const short8*)(lp + 64), a3 = *(const short8*)(lp + 96);

    for (int t = 0; t < 64; t += 2) {
        if ((t & 15) == 0) __syncthreads();    // keep waves converged for B sharing
        // B buffer set 1 <- tile t+1
        const short* p1p = lp + 2048;
        short8 b0 = *(const short8*)(p1p), b1 = *(const short8*)(p1p + 32),
               b2 = *(const short8*)(p1p + 64), b3 = *(const short8*)(p1p + 96);
        // compute tile t (set 0)
        screen_tile(A, a0, a1, a2, a3, rmax);
        // B buffer set 0 <- tile t+2 (tail over-read lands in pnb region, unused)
        const short* p2p = lp + 4096;
        a0 = *(const short8*)(p2p); a1 = *(const short8*)(p2p + 32);
        a2 = *(const short8*)(p2p + 64); a3 = *(const short8*)(p2p + 96);
        // compute tile t+1 (set 1)
        screen_tile(A, b0, b1, b2, b3, rmax);
        lp += 4096;
    }

    #pragma unroll
    for (int rf = 0; rf < 8; ++rf)
        #pragma unroll
        for (int r = 0; r < 4; ++r) {
            float v = rmax[rf][r];
            v = fmaxf(v, __shfl_xor(v, 1));
            v = fmaxf(v, __shfl_xor(v, 2));
            v = fmaxf(v, __shfl_xor(v, 4));
            v = fmaxf(v, __shfl_xor(v, 8));
            if (n16 == 0) {
                int row = rowbase + rf * 16 + quad * 4 + r;
                atomicMax(&mbest[row], ordered_bits(v));
                smax[(size_t)qsplit * 4096 + row] = v;   // exact fp32 strip max
            }
        }
}

// ---------- K3: fused rescreen (row-scan + bf16 re-score + exact rerank) -----
// Grid 1024 = 64 strips x 16 qparts. Each block rebuilds its strip's flagged-
// row list (16 KB smax + 16 KB mbest scan, L2-resident), then re-runs the
// IDENTICAL MFMA chain for flagged rows x its 4 q-tiles. On a threshold hit
// the wave computes the exact fp32 dot inline (same float2 + shfl_xor
// reduction as the old k_rerank -> bit-identical) and atomicMax's best[].
__global__ __launch_bounds__(256, 4) void k_rescreen(const short* __restrict__ pnb,
                                                     const short* __restrict__ qb,
                                                     const unsigned int* __restrict__ mbest,
                                                     const float* __restrict__ smax,
                                                     const float* __restrict__ pn,
                                                     const float* __restrict__ queue,
                                                     unsigned long long* __restrict__ best) {
    __shared__ unsigned short rows[SROWS_CAP];
    __shared__ int nsh;
    int b = blockIdx.x;
    int s = b & 63;                     // strip 0..63
    int qp = b >> 6;                    // 0..15
    int tid = threadIdx.x;
    if (tid == 0) nsh = 0;
    __syncthreads();
    const float* sm = smax + (size_t)s * 4096;
    #pragma unroll
    for (int j = 0; j < 16; ++j) {
        int row = tid + 256 * j;
        float thr = from_ordered(mbest[row]) - EPS_MARGIN;
        if (sm[row] > thr) {
            int pos = atomicAdd(&nsh, 1);
            if (pos < SROWS_CAP) rows[pos] = (unsigned short)row;
        }
    }
    __syncthreads();
    int n = nsh; if (n > SROWS_CAP) n = SROWS_CAP;
    if (n == 0) return;

    int lane = tid & 63, wv = tid >> 6;
    int n16 = lane & 15, quad = lane >> 4;
    int qt = qp * 4 + wv;               // q-tile 0..63 within strip
    int qrow = s * 1024 + qt * 16 + n16;    // this lane's q column index

    // B fragment (identical mapping to k_screen)
    const short* bp = qb + (size_t)qrow * 128 + quad * 8;
    short8 b0 = *(const short8*)(bp);
    short8 b1 = *(const short8*)(bp + 32);
    short8 b2 = *(const short8*)(bp + 64);
    short8 b3 = *(const short8*)(bp + 96);

    for (int base = 0; base < n; base += ROWCHUNK) {
        // Fixed 3 row-tiles (static indexing -> registers); invalid lanes get
        // a clamped A row and thr=+inf so they never hit.
        short8 Af[3][4]; float th[3][4]; int rowC[3][4];
        #pragma unroll
        for (int rt = 0; rt < 3; ++rt) {
            int ia = base + rt * 16 + n16;
            int rA = rows[ia < n ? ia : base];
            const short* ap = pnb + (size_t)rA * 128 + quad * 8;
            #pragma unroll
            for (int kk = 0; kk < 4; ++kk) Af[rt][kk] = *(const short8*)(ap + kk * 32);
            #pragma unroll
            for (int r = 0; r < 4; ++r) {
                int ic = base + rt * 16 + quad * 4 + r;
                if (ic < n) {
                    int rr = rows[ic];
                    rowC[rt][r] = rr;
                    th[rt][r] = from_ordered(mbest[rr]) - EPS_MARGIN;
                } else { rowC[rt][r] = 0; th[rt][r] = 3.0e38f; }
            }
        }
        #pragma unroll
        for (int rt = 0; rt < 3; ++rt) {
            floatx4 zero = {0.0f, 0.0f, 0.0f, 0.0f};
            floatx4 acc = MFMA16(Af[rt][0], b0, zero);
            acc = MFMA16(Af[rt][1], b1, acc);
            acc = MFMA16(Af[rt][2], b2, acc);
            acc = MFMA16(Af[rt][3], b3, acc);
            #pragma unroll
            for (int r = 0; r < 4; ++r) {
                unsigned long long mb = __ballot(acc[r] > th[rt][r]);
                while (mb) {            // rare path: exact fp32 rerank, whole wave
                    int L = __builtin_ctzll(mb);
                    mb &= mb - 1;
                    int row = __shfl(rowC[rt][r], L);
                    int q   = __shfl(qrow, L);
                    float2 a  = ((const float2*)(pn + (size_t)row * 128))[lane];
                    float2 bq = ((const float2*)(queue + (size_t)q * 128))[lane];
                    float d = a.x * bq.x + a.y * bq.y;
                    #pragma unroll
                    for (int o = 32; o; o >>= 1) d += __shfl_xor(d, o);
                    if (lane == 0) {
                        unsigned long long pk = ((unsigned long long)ordered_bits(d) << 32)
                                              | (unsigned long long)(unsigned int)(~q);
                        atomicMax(&best[row], pk);
                    }
                }
            }
        }
    }
}

// ---------- K4: fused gather + A(bf16) @ B(fp32)^T -> exp-partial sums -------
// gridDim.z = 2 selects (M1: nn1 @ p2n^T) / (M2: nn2 @ p1n^T). A rows are
// gathered directly from queue via best[] with bf2f(bf_rne(x)) -- bit-
// identical to the old nnb materialization path.
__global__ __launch_bounds__(256) void k_gemm_lse(const unsigned long long* __restrict__ best,
                                                  const float* __restrict__ queue,
                                                  const float* __restrict__ pn,
                                                  float* __restrict__ sums,
                                                  float* __restrict__ dg) {
    __shared__ __align__(16) float al[64 * S];
    __shared__ __align__(16) float bl[64 * S];
    __shared__ float red[64][17];
    int tid = threadIdx.x;
    int z = blockIdx.z;
    const float* B = pn + (z ? 0 : 2048 * 128);
    float* rowsum = sums + z * 4096;
    float* colsum = sums + z * 4096 + 2048;
    float* diag = dg + z * 2048;
    int arow0 = z * 2048 + blockIdx.x * 64;

    #pragma unroll
    for (int i = tid; i < 1024; i += 256) {
        int r = i >> 4, c = (i & 15) * 8;
        unsigned int idx = (~(unsigned int)(best[arow0 + r] & 0xFFFFFFFFull)) & 0xFFFFu;
        const float* qr = queue + (size_t)idx * 128 + c;
        float4 f0 = *(const float4*)(qr);
        float4 f1 = *(const float4*)(qr + 4);
        float* dst = &al[r * S + c];
        dst[0] = bf2f(bf_rne(f0.x)); dst[1] = bf2f(bf_rne(f0.y));
        dst[2] = bf2f(bf_rne(f0.z)); dst[3] = bf2f(bf_rne(f0.w));
        dst[4] = bf2f(bf_rne(f1.x)); dst[5] = bf2f(bf_rne(f1.y));
        dst[6] = bf2f(bf_rne(f1.z)); dst[7] = bf2f(bf_rne(f1.w));
    }
    const float4* bsrc = (const float4*)(B + (size_t)blockIdx.y * 64 * 128);
    #pragma unroll
    for (int i = tid; i < 2048; i += 256) {
        int r = i >> 5, c = i & 31;
        *(float4*)&bl[r * S + c * 4] = bsrc[i];
    }
    __syncthreads();
    int ty = tid >> 4, tx = tid & 15;
    float acc[4][4] = {};
    #pragma unroll 2
    for (int k = 0; k < 128; k += 4) {
        float4 a[4], b[4];
        #pragma unroll
        for (int i = 0; i < 4; ++i) a[i] = *(const float4*)&al[(ty + 16 * i) * S + k];
        #pragma unroll
        for (int j = 0; j < 4; ++j) b[j] = *(const float4*)&bl[(tx + 16 * j) * S + k];
        #pragma unroll
        for (int i = 0; i < 4; ++i)
            #pragma unroll
            for (int j = 0; j < 4; ++j)
                acc[i][j] += a[i].x * b[j].x + a[i].y * b[j].y +
                             a[i].z * b[j].z + a[i].w * b[j].w;
    }
    int rowbase = blockIdx.x * 64, colbase = blockIdx.y * 64;

    float e[4][4], rs[4], cs[4];
    #pragma unroll
    for (int i = 0; i < 4; ++i) { rs[i] = 0.0f; cs[i] = 0.0f; }
    #pragma unroll
    for (int i = 0; i < 4; ++i)
        #pragma unroll
        for (int j = 0; j < 4; ++j) {
            e[i][j] = __expf(acc[i][j] * SCALE - 10.0f);
            rs[i] += e[i][j];
        }
    #pragma unroll
    for (int j = 0; j < 4; ++j)
        #pragma unroll
        for (int i = 0; i < 4; ++i) cs[j] += e[i][j];

    if (rowbase == colbase && ty == tx) {
        #pragma unroll
        for (int i = 0; i < 4; ++i) diag[rowbase + ty + 16 * i] = acc[i][i];
    }

    #pragma unroll
    for (int i = 0; i < 4; ++i) red[ty + 16 * i][tx] = rs[i];
    __syncthreads();
    if (tid < 64) {
        float s = 0.0f;
        #pragma unroll
        for (int x = 0; x < 16; ++x) s += red[tid][x];
        atomicAdd(&rowsum[rowbase + tid], s);
    }
    __syncthreads();
    #pragma unroll
    for (int j = 0; j < 4; ++j) red[tx + 16 * j][ty] = cs[j];
    __syncthreads();
    if (tid < 64) {
        float s = 0.0f;
        #pragma unroll
        for (int x = 0; x < 16; ++x) s += red[tid][x];
        atomicAdd(&colsum[colbase + tid], s);
    }
}

// ---------- K5: final loss ----------
__global__ void k_final(const float* __restrict__ sums,
                        const float* __restrict__ dg1, const float* __restrict__ dg2,
                        float* __restrict__ out) {
    int idx = blockIdx.x * 256 + threadIdx.x;    // 0..8191
    int seg = idx >> 11, r = idx & 2047;
    float s = sums[seg * 2048 + r];
    float d = (seg < 2) ? dg1[r] : dg2[r];
    out[idx] = 10.0f + logf(s) - d * SCALE;
}

extern "C" void kernel_launch(void* const* d_in, const int* in_sizes, int n_in,
                              void* d_out, int out_size, void* d_ws, size_t ws_size,
                              hipStream_t stream) {
    const float* p1    = (const float*)d_in[0];   // [2048,128]
    const float* p2    = (const float*)d_in[1];   // [2048,128]
    const float* queue = (const float*)d_in[2];   // [65536,128]
    float* out = (float*)d_out;                   // [8192]

    char* w = (char*)d_ws;                        // footprint ~20.1 MiB
    float* pn   = (float*)w;                              // 2 MB fp32 [4096,128]
    float* smax = (float*)(w + (2u << 20));               // 1 MB fp32 [64,4096]
    short* qb   = (short*)(w + (3u << 20));               // 16 MB bf16 [65536,128]
    short* pnb  = (short*)(w + (19u << 20));              // 1 MB bf16 [4096,128]
    char* b2 = w + (20u << 20);
    unsigned int* mbest = (unsigned int*)b2;                        // 16 KB
    unsigned long long* best = (unsigned long long*)(b2 + (16u << 10)); // 32 KB
    float* sums = (float*)(b2 + (48u << 10));                       // 32 KB
    float* dg1  = sums + 8192;                                      // 8 KB
    float* dg2  = dg1 + 2048;                                       // 8 KB

    // 5 launches (was 11): ~10 us/launch overhead measured across rounds 0-5.
    k_prep_qcvt<<<5120, 256, 0, stream>>>(p1, p2, queue, pn, pnb, qb, mbest, best, sums);
    k_screen<<<512, 256, 0, stream>>>(pnb, qb, mbest, smax);
    k_rescreen<<<64 * 16, 256, 0, stream>>>(pnb, qb, mbest, smax, pn, queue, best);
    k_gemm_lse<<<dim3(32, 32, 2), 256, 0, stream>>>(best, queue, pn, sums, dg1);
    k_final<<<32, 256, 0, stream>>>(sums, dg1, dg2, out);
}